// Round 3
// baseline (217.655 us; speedup 1.0000x reference)
//
#include <hip/hip_runtime.h>
#include <cstdint>

#define N_NODES 10000
#define N_EDGES 320000
#define DIN 512
#define DOUT 256
#define DEG_CAP 96   // Poisson(32) tail: P(deg>=96) ~ e^-50; padded-CSR stride
#define AGGB 2500    // agg blocks (4 nodes/block) in combo kernels

using short8 = __attribute__((ext_vector_type(8))) short;
using f32x4  = __attribute__((ext_vector_type(4))) float;
typedef unsigned short ushort_t;

static __device__ __forceinline__ unsigned short f2bf(float f) {
  unsigned u = __builtin_bit_cast(unsigned, f);
  u += 0x7fffu + ((u >> 16) & 1u);   // round-to-nearest-even
  return (unsigned short)(u >> 16);
}
static __device__ __forceinline__ float bf2f(unsigned short s) {
  unsigned u = ((unsigned)s) << 16;
  return __builtin_bit_cast(float, u);
}

// int64-vs-int32 edge_index layout detect (odd u32 words all zero => int64).
static __device__ __forceinline__ int detect64(const unsigned* ei) {
  unsigned z = 0;
  #pragma unroll
  for (int i = 1; i < 32; i += 2) z |= ei[i];
  return z == 0u;
}
static __device__ __forceinline__ int load_idx(const unsigned* ei, int i, int is64) {
  return is64 ? (int)ei[2 * i] : (int)ei[i];
}

// ---------------------------------------------------------------------------
// prep: [0,1250) padded-CSR edge scatter; [1250,2786) five weight
// transposes+bf16 (W0T [256][512]; WlT/WrT [256][256] x2 layers).
// x-cast ELIMINATED: gemm1 reads fp32 x directly.
#define B_EDGE 1250
#define B_W    1536
__global__ __launch_bounds__(256) void prep_all(
    const unsigned* __restrict__ ei, int* __restrict__ cnt,
    int* __restrict__ srcs,
    const float* __restrict__ W0,
    const float* __restrict__ Wl1, const float* __restrict__ Wr1,
    const float* __restrict__ Wl2, const float* __restrict__ Wr2,
    ushort_t* __restrict__ W0T,
    ushort_t* __restrict__ WlT1, ushort_t* __restrict__ WrT1,
    ushort_t* __restrict__ WlT2, ushort_t* __restrict__ WrT2) {
  int b = blockIdx.x;
  if (b < B_EDGE) {
    int is64 = detect64(ei);
    int e = b * 256 + threadIdx.x;            // exact grid: e < N_EDGES
    int d = load_idx(ei, N_EDGES + e, is64);
    int s = load_idx(ei, e, is64);
    int pos = atomicAdd(&cnt[d], 1);
    if (pos < DEG_CAP) srcs[d * DEG_CAP + pos] = s;
  } else {
    int g = (b - B_EDGE) * 256 + threadIdx.x; // 0 .. 3*131072-1
    int mat = g >> 17;
    int r = g & 131071;
    int n = r >> 9, k = r & 511;
    if (mat == 0) {
      W0T[n * 512 + k] = f2bf(W0[k * 256 + n]);
    } else if (mat == 1) {
      if (k < 256) WlT1[n * 256 + k]         = f2bf(Wl1[k * 256 + n]);
      else         WrT1[n * 256 + (k - 256)] = f2bf(Wr1[(k - 256) * 256 + n]);
    } else {
      if (k < 256) WlT2[n * 256 + k]         = f2bf(Wl2[k * 256 + n]);
      else         WrT2[n * 256 + (k - 256)] = f2bf(Wr2[(k - 256) * 256 + n]);
    }
  }
}

// ---------------------------------------------------------------------------
// Padded-CSR mean-aggregate body: one wave/node, lane = 4 cols (uint2),
// 8-edge unroll. h: [M][256] bf16 (5 MB ~ L2).
static __device__ __forceinline__ void agg_body(
    int bid, const ushort_t* __restrict__ h, const int* __restrict__ cnt,
    const int* __restrict__ srcs, ushort_t* __restrict__ mean) {
  int node = bid * 4 + (threadIdx.x >> 6);
  int lane = threadIdx.x & 63;
  if (node >= N_NODES) return;
  int deg = cnt[node];
  int d = (deg < DEG_CAP) ? deg : DEG_CAP;
  int beg = node * DEG_CAP;
  int end = beg + d;
  float a0 = 0.f, a1 = 0.f, a2 = 0.f, a3 = 0.f;
  int j = beg;
  for (; j + 8 <= end; j += 8) {
    int4 sa = *(const int4*)(srcs + j);       // beg % 4 == 0 -> 16B aligned
    int4 sb = *(const int4*)(srcs + j + 4);
    uint2 u0 = *(const uint2*)(h + (size_t)sa.x * 256 + lane * 4);
    uint2 u1 = *(const uint2*)(h + (size_t)sa.y * 256 + lane * 4);
    uint2 u2 = *(const uint2*)(h + (size_t)sa.z * 256 + lane * 4);
    uint2 u3 = *(const uint2*)(h + (size_t)sa.w * 256 + lane * 4);
    uint2 u4 = *(const uint2*)(h + (size_t)sb.x * 256 + lane * 4);
    uint2 u5 = *(const uint2*)(h + (size_t)sb.y * 256 + lane * 4);
    uint2 u6 = *(const uint2*)(h + (size_t)sb.z * 256 + lane * 4);
    uint2 u7 = *(const uint2*)(h + (size_t)sb.w * 256 + lane * 4);
    a0 += bf2f(u0.x & 0xffff) + bf2f(u1.x & 0xffff) + bf2f(u2.x & 0xffff) + bf2f(u3.x & 0xffff);
    a1 += bf2f(u0.x >> 16)    + bf2f(u1.x >> 16)    + bf2f(u2.x >> 16)    + bf2f(u3.x >> 16);
    a2 += bf2f(u0.y & 0xffff) + bf2f(u1.y & 0xffff) + bf2f(u2.y & 0xffff) + bf2f(u3.y & 0xffff);
    a3 += bf2f(u0.y >> 16)    + bf2f(u1.y >> 16)    + bf2f(u2.y >> 16)    + bf2f(u3.y >> 16);
    a0 += bf2f(u4.x & 0xffff) + bf2f(u5.x & 0xffff) + bf2f(u6.x & 0xffff) + bf2f(u7.x & 0xffff);
    a1 += bf2f(u4.x >> 16)    + bf2f(u5.x >> 16)    + bf2f(u6.x >> 16)    + bf2f(u7.x >> 16);
    a2 += bf2f(u4.y & 0xffff) + bf2f(u5.y & 0xffff) + bf2f(u6.y & 0xffff) + bf2f(u7.y & 0xffff);
    a3 += bf2f(u4.y >> 16)    + bf2f(u5.y >> 16)    + bf2f(u6.y >> 16)    + bf2f(u7.y >> 16);
  }
  for (; j + 4 <= end; j += 4) {
    int4 s4 = *(const int4*)(srcs + j);
    uint2 u0 = *(const uint2*)(h + (size_t)s4.x * 256 + lane * 4);
    uint2 u1 = *(const uint2*)(h + (size_t)s4.y * 256 + lane * 4);
    uint2 u2 = *(const uint2*)(h + (size_t)s4.z * 256 + lane * 4);
    uint2 u3 = *(const uint2*)(h + (size_t)s4.w * 256 + lane * 4);
    a0 += bf2f(u0.x & 0xffff) + bf2f(u1.x & 0xffff) + bf2f(u2.x & 0xffff) + bf2f(u3.x & 0xffff);
    a1 += bf2f(u0.x >> 16)    + bf2f(u1.x >> 16)    + bf2f(u2.x >> 16)    + bf2f(u3.x >> 16);
    a2 += bf2f(u0.y & 0xffff) + bf2f(u1.y & 0xffff) + bf2f(u2.y & 0xffff) + bf2f(u3.y & 0xffff);
    a3 += bf2f(u0.y >> 16)    + bf2f(u1.y >> 16)    + bf2f(u2.y >> 16)    + bf2f(u3.y >> 16);
  }
  for (; j < end; ++j) {
    int s0 = srcs[j];
    uint2 u0 = *(const uint2*)(h + (size_t)s0 * 256 + lane * 4);
    a0 += bf2f(u0.x & 0xffff);
    a1 += bf2f(u0.x >> 16);
    a2 += bf2f(u0.y & 0xffff);
    a3 += bf2f(u0.y >> 16);
  }
  float inv = 1.0f / (float)(d > 1 ? d : 1);
  a0 *= inv; a1 *= inv; a2 *= inv; a3 *= inv;
  uint2 o;
  o.x = (unsigned)f2bf(a0) | ((unsigned)f2bf(a1) << 16);
  o.y = (unsigned)f2bf(a2) | ((unsigned)f2bf(a3) << 16);
  *(uint2*)(mean + (size_t)node * 256 + lane * 4) = o;
}

// ---------------------------------------------------------------------------
// Panel-resident GEMM body: C[M x DOUT] = A[M x KDIM] @ BT^T (+bias/addF/
// relu/residual). Block owns a 64-col B panel ([64][KDIM+8] bf16 LDS) and
// 128 M-rows (4 waves x 32). Barrier-free K-loop; XCD swizzle with ROT so
// x-tile -> XCD mapping is identical across kernels regardless of block-id
// offset (offset % 8 compensated by ROT).
// AF32: A is fp32, converted to bf16 in-reg (guarded: x is an input buffer).
// bf16 A is workspace -> unguarded loads are safe.
template<int KDIM, int AF32, int HB, int ADDF, int RELU, int RES,
         int OUTF, int NTF, int OUTB, int ROT>
static __device__ __forceinline__ void gemm_body(
    int gbid, const void* __restrict__ Av, const ushort_t* __restrict__ BT,
    const float* __restrict__ bias, const float* __restrict__ addF,
    const ushort_t* __restrict__ resB, float* __restrict__ outF,
    ushort_t* __restrict__ outB, int M, ushort_t* Bs) {
  constexpr int LDB = KDIM + 8;
  const int sg = gbid >> 5, r32 = gbid & 31;
  const int xt = (sg << 3) + ((r32 + ROT) & 7);
  const int yt = r32 >> 3;
  if (xt >= ((M + 127) >> 7)) return;       // padded tail
  const int tid = threadIdx.x;
  const int lane = tid & 63;
  const int w = tid >> 6;
  const int bn = yt * 64;
  const int mbase = xt * 128 + w * 32;

  constexpr int CPR = KDIM / 8;             // uint4 chunks per B row
  #pragma unroll
  for (int i = 0; i < (64 * CPR) / 256; ++i) {
    int c = i * 256 + tid;
    int row = c / CPR;
    int c8 = (c % CPR) * 8;
    uint4 bv = *(const uint4*)(BT + (size_t)(bn + row) * KDIM + c8);
    *(uint4*)&Bs[row * LDB + c8] = bv;
  }
  __syncthreads();

  f32x4 acc[2][4] = {};
  const int mrow = lane & 15;
  const int k8 = (lane >> 4) * 8;

  #pragma unroll
  for (int kt = 0; kt < KDIM; kt += 32) {
    short8 a[2], b[4];
    #pragma unroll
    for (int s = 0; s < 2; ++s) {
      int row = mbase + s * 16 + mrow;
      if (AF32) {
        const float* Af = (const float*)Av;
        float4 f0 = {}, f1 = {};
        if (row < M) {
          const float* p = Af + (size_t)row * KDIM + kt + k8;
          f0 = *(const float4*)p;
          f1 = *(const float4*)(p + 4);
        }
        short8 av;
        av[0] = (short)f2bf(f0.x); av[1] = (short)f2bf(f0.y);
        av[2] = (short)f2bf(f0.z); av[3] = (short)f2bf(f0.w);
        av[4] = (short)f2bf(f1.x); av[5] = (short)f2bf(f1.y);
        av[6] = (short)f2bf(f1.z); av[7] = (short)f2bf(f1.w);
        a[s] = av;
      } else {
        const ushort_t* Ab = (const ushort_t*)Av;
        a[s] = *(const short8*)(Ab + (size_t)row * KDIM + kt + k8);
      }
    }
    #pragma unroll
    for (int ni = 0; ni < 4; ++ni)
      b[ni] = *(const short8*)&Bs[(ni * 16 + mrow) * LDB + kt + k8];
    #pragma unroll
    for (int s = 0; s < 2; ++s)
      #pragma unroll
      for (int ni = 0; ni < 4; ++ni)
        acc[s][ni] = __builtin_amdgcn_mfma_f32_16x16x32_bf16(a[s], b[ni], acc[s][ni], 0, 0, 0);
  }

  // C/D layout: col = lane&15, row = (lane>>4)*4 + reg   [m89-verified]
  const int cq = lane >> 4;
  const int ccol = lane & 15;
  #pragma unroll
  for (int ni = 0; ni < 4; ++ni) {
    int gcol = bn + ni * 16 + ccol;
    float bv = HB ? bias[gcol] : 0.f;
    #pragma unroll
    for (int s = 0; s < 2; ++s) {
      #pragma unroll
      for (int r = 0; r < 4; ++r) {
        int grow = mbase + s * 16 + cq * 4 + r;
        if (grow < M) {
          size_t idx = (size_t)grow * DOUT + gcol;
          float v = acc[s][ni][r];
          if (HB)   v += bv;
          if (ADDF) v += addF[idx];
          if (RELU) v = fmaxf(v, 0.f);
          if (RES)  v += bf2f(resB[idx]);
          if (OUTF) {
            if (NTF) __builtin_nontemporal_store(v, &outF[idx]);
            else     outF[idx] = v;
          }
          if (OUTB) outB[idx] = f2bf(v);
        }
      }
    }
  }
}

// ---------------------------------------------------------------------------
// h = x(fp32) @ W0T + b0 -> hb bf16.  K=512, 66.5 KB LDS.
__global__ __launch_bounds__(256) void gemm1_k(
    const float* __restrict__ x, const ushort_t* __restrict__ W0T,
    const float* __restrict__ b0, ushort_t* __restrict__ hb) {
  __shared__ ushort_t Bs[64 * 520];
  gemm_body<512, 1, 1, 0, 0, 0, 0, 0, 1, 0>(blockIdx.x, x, W0T, b0, nullptr,
                                            nullptr, nullptr, hb, N_NODES, Bs);
}

// combo: blocks [0,AGGB) mean-aggregate h->mean; blocks [AGGB,AGGB+320)
// t = h @ WrT + bias (K=256, fp32 out, exact partial). The R-gemm rides
// under the latency-bound gather. ROT=4 compensates AGGB%8==4 so x-tiles
// keep the same XCD as the other gemms.
__global__ __launch_bounds__(256) void combo_k(
    const ushort_t* __restrict__ h, const int* __restrict__ cnt,
    const int* __restrict__ srcs, ushort_t* __restrict__ mean,
    const ushort_t* __restrict__ BT, const float* __restrict__ bias,
    float* __restrict__ t) {
  __shared__ ushort_t Bs[64 * 264];
  if (blockIdx.x < AGGB) {
    agg_body(blockIdx.x, h, cnt, srcs, mean);
  } else {
    gemm_body<256, 0, 1, 0, 0, 0, 1, 0, 0, 4>(blockIdx.x - AGGB, h, BT, bias,
                                              nullptr, nullptr, t, nullptr,
                                              N_NODES, Bs);
  }
}

// L-gemm: out = [relu](mean @ WlT + t) + res.  K=256.
template<int RELU, int OUTB>
__global__ __launch_bounds__(256) void gemmL_k(
    const ushort_t* __restrict__ A, const ushort_t* __restrict__ BT,
    const float* __restrict__ t, const ushort_t* __restrict__ res,
    float* __restrict__ outF, ushort_t* __restrict__ outB) {
  __shared__ ushort_t Bs[64 * 264];
  gemm_body<256, 0, 0, 1, RELU, 1, 1, 1, OUTB, 0>(blockIdx.x, A, BT, nullptr,
                                                  t, res, outF, outB,
                                                  N_NODES, Bs);
}

// ---------------------------------------------------------------------------
extern "C" void kernel_launch(void* const* d_in, const int* in_sizes, int n_in,
                              void* d_out, int out_size, void* d_ws, size_t ws_size,
                              hipStream_t stream) {
  const float*    x   = (const float*)d_in[0];
  const unsigned* ei  = (const unsigned*)d_in[1];
  const float*    W0  = (const float*)d_in[2];
  const float*    b0  = (const float*)d_in[3];
  const float*    Wl1 = (const float*)d_in[4];
  const float*    bl1 = (const float*)d_in[5];
  const float*    Wr1 = (const float*)d_in[6];
  const float*    Wl2 = (const float*)d_in[7];
  const float*    bl2 = (const float*)d_in[8];
  const float*    Wr2 = (const float*)d_in[9];

  char* ws = (char*)d_ws;
  size_t off = 0;
  auto alloc = [&](size_t bytes) {
    char* p = ws + off;
    off += (bytes + 255) & ~(size_t)255;
    return p;
  };
  ushort_t* hb   = (ushort_t*)alloc((size_t)N_NODES * 256 * 2);  // h bf16
  ushort_t* o1b  = (ushort_t*)alloc((size_t)N_NODES * 256 * 2);  // out1 bf16
  ushort_t* mb   = (ushort_t*)alloc((size_t)N_NODES * 256 * 2);  // mean (reused)
  float*    t    = (float*)   alloc((size_t)N_NODES * 256 * 4);  // h@Wr partial (reused)
  ushort_t* W0T  = (ushort_t*)alloc(256 * 512 * 2);
  ushort_t* WlT1 = (ushort_t*)alloc(256 * 256 * 2);
  ushort_t* WrT1 = (ushort_t*)alloc(256 * 256 * 2);
  ushort_t* WlT2 = (ushort_t*)alloc(256 * 256 * 2);
  ushort_t* WrT2 = (ushort_t*)alloc(256 * 256 * 2);
  int* cnt  = (int*)alloc(N_NODES * 4);
  int* srcs = (int*)alloc((size_t)N_NODES * DEG_CAP * 4);

  float* out1 = (float*)d_out;
  float* out2 = out1 + (size_t)N_NODES * DOUT;

  hipMemsetAsync(cnt, 0, N_NODES * 4, stream);
  // edge scatter + all weight transposes (no x-cast)
  prep_all<<<B_EDGE + B_W, 256, 0, stream>>>(ei, cnt, srcs,
                                             W0, Wl1, Wr1, Wl2, Wr2,
                                             W0T, WlT1, WrT1, WlT2, WrT2);
  // h = x @ W0 + b0  (fp32 A read directly; bf16 out only)
  gemm1_k<<<320, 256, 0, stream>>>(x, W0T, b0, hb);
  // mean1 = scatter-mean(h)  ||  t = h @ Wr1 + bl1
  combo_k<<<AGGB + 320, 256, 0, stream>>>(hb, cnt, srcs, mb, WrT1, bl1, t);
  // out1 = relu(mean1 @ Wl1 + t) + h
  gemmL_k<1, 1><<<320, 256, 0, stream>>>(mb, WlT1, t, hb, out1, o1b);
  // mean2 = scatter-mean(out1)  ||  t = out1 @ Wr2 + bl2
  combo_k<<<AGGB + 320, 256, 0, stream>>>(o1b, cnt, srcs, mb, WrT2, bl2, t);
  // out2 = mean2 @ Wl2 + t + out1
  gemmL_k<0, 0><<<320, 256, 0, stream>>>(mb, WlT2, t, o1b, out2, nullptr);
}

// Round 4
// 196.009 us; speedup vs baseline: 1.1104x; 1.1104x over previous
//
#include <hip/hip_runtime.h>
#include <cstdint>

#define N_NODES 10000
#define N_EDGES 320000
#define DIN 512
#define DOUT 256
#define DEG_CAP 96   // Poisson(32) tail: P(deg>=96) ~ e^-50; padded-CSR stride

using short8 = __attribute__((ext_vector_type(8))) short;
using f32x4  = __attribute__((ext_vector_type(4))) float;
typedef unsigned short ushort_t;

static __device__ __forceinline__ unsigned short f2bf(float f) {
  unsigned u = __builtin_bit_cast(unsigned, f);
  u += 0x7fffu + ((u >> 16) & 1u);   // round-to-nearest-even
  return (unsigned short)(u >> 16);
}
static __device__ __forceinline__ float bf2f(unsigned short s) {
  unsigned u = ((unsigned)s) << 16;
  return __builtin_bit_cast(float, u);
}

// int64-vs-int32 edge_index layout detect (odd u32 words all zero => int64).
static __device__ __forceinline__ int detect64(const unsigned* ei) {
  unsigned z = 0;
  #pragma unroll
  for (int i = 1; i < 32; i += 2) z |= ei[i];
  return z == 0u;
}
static __device__ __forceinline__ int load_idx(const unsigned* ei, int i, int is64) {
  return is64 ? (int)ei[2 * i] : (int)ei[i];
}

// ---------------------------------------------------------------------------
// Fused setup: [0,1250) padded-CSR edge scatter (single pass, atomic cursor
// doubles as degree count); [1250,2786) weight transpose+bf16; [2786,7786)
// x fp32 -> bf16 cast.
#define B_EDGE 1250
#define B_W    1536
#define B_X    5000
__global__ __launch_bounds__(256) void prep_all(
    const unsigned* __restrict__ ei, int* __restrict__ cnt,
    int* __restrict__ srcs,
    const float* __restrict__ x, ushort_t* __restrict__ xb,
    const float* __restrict__ W0,
    const float* __restrict__ Wl1, const float* __restrict__ Wr1,
    const float* __restrict__ Wl2, const float* __restrict__ Wr2,
    ushort_t* __restrict__ W0T, ushort_t* __restrict__ WT1,
    ushort_t* __restrict__ WT2) {
  int b = blockIdx.x;
  if (b < B_EDGE) {
    int is64 = detect64(ei);
    int e = b * 256 + threadIdx.x;            // exact grid: e < N_EDGES
    int d = load_idx(ei, N_EDGES + e, is64);
    int s = load_idx(ei, e, is64);
    int pos = atomicAdd(&cnt[d], 1);
    if (pos < DEG_CAP) srcs[d * DEG_CAP + pos] = s;
  } else if (b < B_EDGE + B_W) {
    int g = (b - B_EDGE) * 256 + threadIdx.x; // 0 .. 3*131072-1
    int mat = g >> 17;
    int r = g & 131071;
    int n = r >> 9, k = r & 511;
    float v;
    ushort_t* dst;
    if (mat == 0)      { v = W0[k * 256 + n]; dst = W0T; }
    else if (mat == 1) { v = (k < 256) ? Wl1[k * 256 + n] : Wr1[(k - 256) * 256 + n]; dst = WT1; }
    else               { v = (k < 256) ? Wl2[k * 256 + n] : Wr2[(k - 256) * 256 + n]; dst = WT2; }
    dst[r] = f2bf(v);
  } else {
    int g = (b - B_EDGE - B_W) * 256 + threadIdx.x;  // 0 .. 1,280,000-1
    float4 f = *(const float4*)(x + (size_t)g * 4);
    uint2 o;
    o.x = (unsigned)f2bf(f.x) | ((unsigned)f2bf(f.y) << 16);
    o.y = (unsigned)f2bf(f.z) | ((unsigned)f2bf(f.w) << 16);
    *(uint2*)(xb + (size_t)g * 4) = o;
  }
}

// ---------------------------------------------------------------------------
// Padded-CSR mean-aggregate: one wave/node, lane = 4 cols (uint2), 16-edge
// unroll (16 independent row-gathers + 4 int4 index loads in flight --
// gather is latency-bound, not BW-bound: 164 MB of L2-resident traffic).
__global__ __launch_bounds__(256) void agg_mean(const ushort_t* __restrict__ h,
                                                const int* __restrict__ cnt,
                                                const int* __restrict__ srcs,
                                                ushort_t* __restrict__ mean) {
  int node = blockIdx.x * 4 + (threadIdx.x >> 6);
  int lane = threadIdx.x & 63;
  if (node >= N_NODES) return;
  int deg = cnt[node];
  int d = (deg < DEG_CAP) ? deg : DEG_CAP;
  int beg = node * DEG_CAP;
  int end = beg + d;
  float a0 = 0.f, a1 = 0.f, a2 = 0.f, a3 = 0.f;
  int j = beg;
  for (; j + 16 <= end; j += 16) {
    int4 sa = *(const int4*)(srcs + j);       // beg % 4 == 0 -> 16B aligned
    int4 sb = *(const int4*)(srcs + j + 4);
    int4 sc = *(const int4*)(srcs + j + 8);
    int4 sd = *(const int4*)(srcs + j + 12);
    uint2 u0 = *(const uint2*)(h + (size_t)sa.x * 256 + lane * 4);
    uint2 u1 = *(const uint2*)(h + (size_t)sa.y * 256 + lane * 4);
    uint2 u2 = *(const uint2*)(h + (size_t)sa.z * 256 + lane * 4);
    uint2 u3 = *(const uint2*)(h + (size_t)sa.w * 256 + lane * 4);
    uint2 u4 = *(const uint2*)(h + (size_t)sb.x * 256 + lane * 4);
    uint2 u5 = *(const uint2*)(h + (size_t)sb.y * 256 + lane * 4);
    uint2 u6 = *(const uint2*)(h + (size_t)sb.z * 256 + lane * 4);
    uint2 u7 = *(const uint2*)(h + (size_t)sb.w * 256 + lane * 4);
    uint2 u8 = *(const uint2*)(h + (size_t)sc.x * 256 + lane * 4);
    uint2 u9 = *(const uint2*)(h + (size_t)sc.y * 256 + lane * 4);
    uint2 ua = *(const uint2*)(h + (size_t)sc.z * 256 + lane * 4);
    uint2 ub = *(const uint2*)(h + (size_t)sc.w * 256 + lane * 4);
    uint2 uc = *(const uint2*)(h + (size_t)sd.x * 256 + lane * 4);
    uint2 ud = *(const uint2*)(h + (size_t)sd.y * 256 + lane * 4);
    uint2 ue = *(const uint2*)(h + (size_t)sd.z * 256 + lane * 4);
    uint2 uf = *(const uint2*)(h + (size_t)sd.w * 256 + lane * 4);
    a0 += bf2f(u0.x & 0xffff) + bf2f(u1.x & 0xffff) + bf2f(u2.x & 0xffff) + bf2f(u3.x & 0xffff);
    a1 += bf2f(u0.x >> 16)    + bf2f(u1.x >> 16)    + bf2f(u2.x >> 16)    + bf2f(u3.x >> 16);
    a2 += bf2f(u0.y & 0xffff) + bf2f(u1.y & 0xffff) + bf2f(u2.y & 0xffff) + bf2f(u3.y & 0xffff);
    a3 += bf2f(u0.y >> 16)    + bf2f(u1.y >> 16)    + bf2f(u2.y >> 16)    + bf2f(u3.y >> 16);
    a0 += bf2f(u4.x & 0xffff) + bf2f(u5.x & 0xffff) + bf2f(u6.x & 0xffff) + bf2f(u7.x & 0xffff);
    a1 += bf2f(u4.x >> 16)    + bf2f(u5.x >> 16)    + bf2f(u6.x >> 16)    + bf2f(u7.x >> 16);
    a2 += bf2f(u4.y & 0xffff) + bf2f(u5.y & 0xffff) + bf2f(u6.y & 0xffff) + bf2f(u7.y & 0xffff);
    a3 += bf2f(u4.y >> 16)    + bf2f(u5.y >> 16)    + bf2f(u6.y >> 16)    + bf2f(u7.y >> 16);
    a0 += bf2f(u8.x & 0xffff) + bf2f(u9.x & 0xffff) + bf2f(ua.x & 0xffff) + bf2f(ub.x & 0xffff);
    a1 += bf2f(u8.x >> 16)    + bf2f(u9.x >> 16)    + bf2f(ua.x >> 16)    + bf2f(ub.x >> 16);
    a2 += bf2f(u8.y & 0xffff) + bf2f(u9.y & 0xffff) + bf2f(ua.y & 0xffff) + bf2f(ub.y & 0xffff);
    a3 += bf2f(u8.y >> 16)    + bf2f(u9.y >> 16)    + bf2f(ua.y >> 16)    + bf2f(ub.y >> 16);
    a0 += bf2f(uc.x & 0xffff) + bf2f(ud.x & 0xffff) + bf2f(ue.x & 0xffff) + bf2f(uf.x & 0xffff);
    a1 += bf2f(uc.x >> 16)    + bf2f(ud.x >> 16)    + bf2f(ue.x >> 16)    + bf2f(uf.x >> 16);
    a2 += bf2f(uc.y & 0xffff) + bf2f(ud.y & 0xffff) + bf2f(ue.y & 0xffff) + bf2f(uf.y & 0xffff);
    a3 += bf2f(uc.y >> 16)    + bf2f(ud.y >> 16)    + bf2f(ue.y >> 16)    + bf2f(uf.y >> 16);
  }
  for (; j + 8 <= end; j += 8) {
    int4 sa = *(const int4*)(srcs + j);
    int4 sb = *(const int4*)(srcs + j + 4);
    uint2 u0 = *(const uint2*)(h + (size_t)sa.x * 256 + lane * 4);
    uint2 u1 = *(const uint2*)(h + (size_t)sa.y * 256 + lane * 4);
    uint2 u2 = *(const uint2*)(h + (size_t)sa.z * 256 + lane * 4);
    uint2 u3 = *(const uint2*)(h + (size_t)sa.w * 256 + lane * 4);
    uint2 u4 = *(const uint2*)(h + (size_t)sb.x * 256 + lane * 4);
    uint2 u5 = *(const uint2*)(h + (size_t)sb.y * 256 + lane * 4);
    uint2 u6 = *(const uint2*)(h + (size_t)sb.z * 256 + lane * 4);
    uint2 u7 = *(const uint2*)(h + (size_t)sb.w * 256 + lane * 4);
    a0 += bf2f(u0.x & 0xffff) + bf2f(u1.x & 0xffff) + bf2f(u2.x & 0xffff) + bf2f(u3.x & 0xffff);
    a1 += bf2f(u0.x >> 16)    + bf2f(u1.x >> 16)    + bf2f(u2.x >> 16)    + bf2f(u3.x >> 16);
    a2 += bf2f(u0.y & 0xffff) + bf2f(u1.y & 0xffff) + bf2f(u2.y & 0xffff) + bf2f(u3.y & 0xffff);
    a3 += bf2f(u0.y >> 16)    + bf2f(u1.y >> 16)    + bf2f(u2.y >> 16)    + bf2f(u3.y >> 16);
    a0 += bf2f(u4.x & 0xffff) + bf2f(u5.x & 0xffff) + bf2f(u6.x & 0xffff) + bf2f(u7.x & 0xffff);
    a1 += bf2f(u4.x >> 16)    + bf2f(u5.x >> 16)    + bf2f(u6.x >> 16)    + bf2f(u7.x >> 16);
    a2 += bf2f(u4.y & 0xffff) + bf2f(u5.y & 0xffff) + bf2f(u6.y & 0xffff) + bf2f(u7.y & 0xffff);
    a3 += bf2f(u4.y >> 16)    + bf2f(u5.y >> 16)    + bf2f(u6.y >> 16)    + bf2f(u7.y >> 16);
  }
  for (; j + 4 <= end; j += 4) {
    int4 s4 = *(const int4*)(srcs + j);
    uint2 u0 = *(const uint2*)(h + (size_t)s4.x * 256 + lane * 4);
    uint2 u1 = *(const uint2*)(h + (size_t)s4.y * 256 + lane * 4);
    uint2 u2 = *(const uint2*)(h + (size_t)s4.z * 256 + lane * 4);
    uint2 u3 = *(const uint2*)(h + (size_t)s4.w * 256 + lane * 4);
    a0 += bf2f(u0.x & 0xffff) + bf2f(u1.x & 0xffff) + bf2f(u2.x & 0xffff) + bf2f(u3.x & 0xffff);
    a1 += bf2f(u0.x >> 16)    + bf2f(u1.x >> 16)    + bf2f(u2.x >> 16)    + bf2f(u3.x >> 16);
    a2 += bf2f(u0.y & 0xffff) + bf2f(u1.y & 0xffff) + bf2f(u2.y & 0xffff) + bf2f(u3.y & 0xffff);
    a3 += bf2f(u0.y >> 16)    + bf2f(u1.y >> 16)    + bf2f(u2.y >> 16)    + bf2f(u3.y >> 16);
  }
  for (; j < end; ++j) {
    int s0 = srcs[j];
    uint2 u0 = *(const uint2*)(h + (size_t)s0 * 256 + lane * 4);
    a0 += bf2f(u0.x & 0xffff);
    a1 += bf2f(u0.x >> 16);
    a2 += bf2f(u0.y & 0xffff);
    a3 += bf2f(u0.y >> 16);
  }
  float inv = 1.0f / (float)(d > 1 ? d : 1);
  a0 *= inv; a1 *= inv; a2 *= inv; a3 *= inv;
  uint2 o;
  o.x = (unsigned)f2bf(a0) | ((unsigned)f2bf(a1) << 16);
  o.y = (unsigned)f2bf(a2) | ((unsigned)f2bf(a3) << 16);
  *(uint2*)(mean + (size_t)node * 256 + lane * 4) = o;
}

// ---------------------------------------------------------------------------
// Panel-resident GEMM: C[M x 256] = A[M x 512] @ BT^T (+bias, relu?, +bf16
// addend?). Block owns a 64-col B panel (64x512 bf16 in LDS, loaded ONCE,
// row pad +8) and 128 M-rows (4 waves x 32). Barrier-free K-loop.
// 1D grid with XCD swizzle: all 4 y-panels of an x-tile land on the SAME XCD
// (bid%8 invariant within group) -> A rows fetched once per XCD, reread from
// its private L2 instead of 4x from HBM/LLC.
// SPLIT_A: A = [A0 | A1] split at k=256 (both ld 256); else A0 with ld 512.
// A-loads are unguarded: rows >= M read adjacent workspace (safe, results
// discarded at the guarded store).
template<int DO_RELU, int HAS_ADD, int HAS_OUTF, int HAS_OUTB, int SPLIT_A>
__global__ __launch_bounds__(256) void gemm_pan(
    const ushort_t* __restrict__ A0, const ushort_t* __restrict__ A1,
    const ushort_t* __restrict__ BT, const float* __restrict__ bias,
    const ushort_t* __restrict__ addB,
    float* __restrict__ outF, ushort_t* __restrict__ outB, int M) {
  __shared__ ushort_t Bs[64 * 520];   // +8 pad

  // XCD-aware decode: super-group of 32 bids = 8 x-tiles x 4 y-panels,
  // arranged so bid % 8 == x % 8 for all 4 y of an x.
  const int bid = blockIdx.x;
  const int sg  = bid >> 5;
  const int r32 = bid & 31;
  const int xt  = (sg << 3) + (r32 & 7);
  const int yt  = r32 >> 3;
  const int xtiles = (M + 127) >> 7;
  if (xt >= xtiles) return;           // padded tail blocks

  const int tid  = threadIdx.x;
  const int lane = tid & 63;
  const int w    = tid >> 6;
  const int bn   = yt * 64;
  const int mbase = xt * 128 + w * 32;

  // stage B panel once: 64 rows x 512 k = 4096 uint4 chunks, 16 per thread
  #pragma unroll
  for (int i = 0; i < 16; ++i) {
    int c = i * 256 + tid;
    int row = c >> 6;
    int c8  = (c & 63) * 8;
    uint4 bv = *(const uint4*)(BT + (size_t)(bn + row) * 512 + c8);
    *(uint4*)&Bs[row * 520 + c8] = bv;
  }
  __syncthreads();

  f32x4 acc[2][4] = {};
  const int mrow = lane & 15;
  const int k8   = (lane >> 4) * 8;

  #pragma unroll
  for (int kt = 0; kt < 512; kt += 32) {
    const ushort_t* Asrc;
    int acol, ald;
    if (SPLIT_A) {
      if (kt < 256) { Asrc = A0; acol = kt; } else { Asrc = A1; acol = kt - 256; }
      ald = 256;
    } else {
      Asrc = A0; acol = kt; ald = 512;
    }
    short8 a[2], b[4];
    #pragma unroll
    for (int s = 0; s < 2; ++s) {
      int row = mbase + s * 16 + mrow;
      a[s] = *(const short8*)(Asrc + (size_t)row * ald + acol + k8);
    }
    #pragma unroll
    for (int ni = 0; ni < 4; ++ni)
      b[ni] = *(const short8*)&Bs[(ni * 16 + mrow) * 520 + kt + k8];
    #pragma unroll
    for (int s = 0; s < 2; ++s)
      #pragma unroll
      for (int ni = 0; ni < 4; ++ni)
        acc[s][ni] = __builtin_amdgcn_mfma_f32_16x16x32_bf16(a[s], b[ni], acc[s][ni], 0, 0, 0);
  }

  // C/D layout: col = lane&15, row = (lane>>4)*4 + reg   [m89-verified]
  const int cq   = lane >> 4;
  const int ccol = lane & 15;
  #pragma unroll
  for (int ni = 0; ni < 4; ++ni) {
    int gcol = bn + ni * 16 + ccol;
    float bv = bias[gcol];
    #pragma unroll
    for (int s = 0; s < 2; ++s) {
      #pragma unroll
      for (int r = 0; r < 4; ++r) {
        int grow = mbase + s * 16 + cq * 4 + r;
        if (grow < M) {
          float v = acc[s][ni][r] + bv;
          if (DO_RELU) v = fmaxf(v, 0.f);
          if (HAS_ADD) v += bf2f(addB[(size_t)grow * DOUT + gcol]);
          // final fp32 outputs are never re-read on device -> nontemporal
          if (HAS_OUTF) __builtin_nontemporal_store(v, &outF[(size_t)grow * DOUT + gcol]);
          if (HAS_OUTB) outB[(size_t)grow * DOUT + gcol] = f2bf(v);
        }
      }
    }
  }
}

// ---------------------------------------------------------------------------
extern "C" void kernel_launch(void* const* d_in, const int* in_sizes, int n_in,
                              void* d_out, int out_size, void* d_ws, size_t ws_size,
                              hipStream_t stream) {
  const float*    x   = (const float*)d_in[0];
  const unsigned* ei  = (const unsigned*)d_in[1];
  const float*    W0  = (const float*)d_in[2];
  const float*    b0  = (const float*)d_in[3];
  const float*    Wl1 = (const float*)d_in[4];
  const float*    bl1 = (const float*)d_in[5];
  const float*    Wr1 = (const float*)d_in[6];
  const float*    Wl2 = (const float*)d_in[7];
  const float*    bl2 = (const float*)d_in[8];
  const float*    Wr2 = (const float*)d_in[9];

  char* ws = (char*)d_ws;
  size_t off = 0;
  auto alloc = [&](size_t bytes) {
    char* p = ws + off;
    off += (bytes + 255) & ~(size_t)255;
    return p;
  };
  ushort_t* xb  = (ushort_t*)alloc((size_t)N_NODES * 512 * 2);  // x bf16 [M][512]
  ushort_t* hb  = (ushort_t*)alloc((size_t)N_NODES * 256 * 2);  // h bf16
  ushort_t* o1b = (ushort_t*)alloc((size_t)N_NODES * 256 * 2);  // out1 bf16
  ushort_t* mb  = (ushort_t*)alloc((size_t)N_NODES * 256 * 2);  // mean (reused)
  ushort_t* W0T = (ushort_t*)alloc(256 * 512 * 2);
  ushort_t* WT1 = (ushort_t*)alloc(256 * 512 * 2);
  ushort_t* WT2 = (ushort_t*)alloc(256 * 512 * 2);
  int* cnt    = (int*)alloc(N_NODES * 4);
  int* srcs   = (int*)alloc((size_t)N_NODES * DEG_CAP * 4);

  float* out1 = (float*)d_out;
  float* out2 = out1 + (size_t)N_NODES * DOUT;

  hipMemsetAsync(cnt, 0, N_NODES * 4, stream);
  // single edge pass: padded-CSR scatter (cnt doubles as degree) + weight
  // transpose + x cast, all in one grid
  prep_all<<<B_EDGE + B_W + B_X, 256, 0, stream>>>(ei, cnt, srcs, x, xb,
                                                   W0, Wl1, Wr1, Wl2, Wr2,
                                                   W0T, WT1, WT2);

  // 1D swizzled grid: xtiles=79 padded to 80 -> 320 blocks (4 dead)
  const int GG = 320;
  // h = x @ W0 + b0  (bf16 only; fp32 h not needed downstream)
  gemm_pan<0, 0, 0, 1, 0><<<GG, 256, 0, stream>>>(xb, nullptr, W0T, b0, nullptr,
                                                  nullptr, hb, N_NODES);
  // mean1 = scatter-mean(h)
  agg_mean<<<(N_NODES + 3) / 4, 256, 0, stream>>>(hb, cnt, srcs, mb);
  // out1 = relu([mean1|h] @ [Wl1;Wr1] + bl1) + h   (h addend in bf16)
  gemm_pan<1, 1, 1, 1, 1><<<GG, 256, 0, stream>>>(mb, hb, WT1, bl1, hb,
                                                  out1, o1b, N_NODES);
  // mean2 = scatter-mean(out1)
  agg_mean<<<(N_NODES + 3) / 4, 256, 0, stream>>>(o1b, cnt, srcs, mb);
  // out2 = [mean2|out1] @ [Wl2;Wr2] + bl2 + out1   (out1 addend in bf16)
  gemm_pan<0, 1, 1, 0, 1><<<GG, 256, 0, stream>>>(mb, o1b, WT2, bl2, o1b,
                                                  out2, nullptr, N_NODES);
}